// Round 12
// baseline (427.749 us; speedup 1.0000x reference)
//
#include <hip/hip_runtime.h>
#include <cstdint>
#include <cstddef>

typedef unsigned short ushort_t;
typedef __attribute__((ext_vector_type(8))) short short8;   // 8 bf16 (4 VGPRs)
typedef __attribute__((ext_vector_type(4))) float f32x4;    // MFMA acc

// Problem constants (from reference)
constexpr int N_NODES = 100000;
constexpr int N_EDGES = 1000000;

// ---- bf16 pack/unpack (RNE) ----
__device__ __forceinline__ unsigned bf16rne(float f) {
    unsigned u = __float_as_uint(f);
    return (u + 0x7FFFu + ((u >> 16) & 1u)) >> 16;
}
__device__ __forceinline__ unsigned pack2(float lo, float hi) {
    return bf16rne(lo) | (bf16rne(hi) << 16);
}
__device__ __forceinline__ float unpack_lo(unsigned u) { return __uint_as_float(u << 16); }
__device__ __forceinline__ float unpack_hi(unsigned u) { return __uint_as_float(u & 0xFFFF0000u); }

// ============================ CSR build ============================
__global__ void zero_int(int* __restrict__ p, int n) {
    int i = blockIdx.x * blockDim.x + threadIdx.x;
    if (i < n) p[i] = 0;
}

__global__ void hist_kernel(const int* __restrict__ dst, int* __restrict__ cnt) {
    int i = blockIdx.x * blockDim.x + threadIdx.x;
    if (i < N_EDGES) atomicAdd(&cnt[dst[i]], 1);
}

__global__ __launch_bounds__(256) void scan1(const int* __restrict__ cnt,
    int* __restrict__ excl, int* __restrict__ bsum, int n) {
    __shared__ int sh[256];
    int b = blockIdx.x, t = threadIdx.x;
    int base = b * 1024 + t * 4;
    int v0 = (base + 0 < n) ? cnt[base + 0] : 0;
    int v1 = (base + 1 < n) ? cnt[base + 1] : 0;
    int v2 = (base + 2 < n) ? cnt[base + 2] : 0;
    int v3 = (base + 3 < n) ? cnt[base + 3] : 0;
    int s = v0 + v1 + v2 + v3;
    sh[t] = s;
    __syncthreads();
    for (int off = 1; off < 256; off <<= 1) {
        int val = (t >= off) ? sh[t - off] : 0;
        __syncthreads();
        sh[t] += val;
        __syncthreads();
    }
    int prefix = sh[t] - s;
    if (t == 255) bsum[b] = sh[255];
    if (base + 0 < n) excl[base + 0] = prefix;
    if (base + 1 < n) excl[base + 1] = prefix + v0;
    if (base + 2 < n) excl[base + 2] = prefix + v0 + v1;
    if (base + 3 < n) excl[base + 3] = prefix + v0 + v1 + v2;
}

__global__ __launch_bounds__(128) void scan2(int* __restrict__ bsum, int nb) {
    __shared__ int sh[128];
    int t = threadIdx.x;
    int v = (t < nb) ? bsum[t] : 0;
    sh[t] = v;
    __syncthreads();
    for (int off = 1; off < 128; off <<= 1) {
        int val = (t >= off) ? sh[t - off] : 0;
        __syncthreads();
        sh[t] += val;
        __syncthreads();
    }
    if (t < nb) bsum[t] = sh[t] - v;
}

__global__ void scan3(const int* __restrict__ excl, const int* __restrict__ bsum,
                      int* __restrict__ rowptr, int* __restrict__ cursor, int n) {
    int i = blockIdx.x * blockDim.x + threadIdx.x;
    if (i < n) { int r = excl[i] + bsum[i >> 10]; rowptr[i] = r; cursor[i] = r; }
    if (i == n) rowptr[n] = N_EDGES;
}

__global__ void scatter_kernel(const int* __restrict__ dst, const int* __restrict__ src,
                               int* __restrict__ cursor, int2* __restrict__ es) {
    int e = blockIdx.x * blockDim.x + threadIdx.x;
    if (e < N_EDGES) {
        int p = atomicAdd(&cursor[dst[e]], 1);
        es[p] = make_int2(e, src[e]);
    }
}

// ============================ Wg build (both layers, one launch) ============================
template<int KDIM, int H>
__device__ void wg_dev(const float* __restrict__ Wq, const float* __restrict__ bq,
                       const float* __restrict__ We,
                       float* __restrict__ Wg, float* __restrict__ bg) {
    __shared__ float wq[KDIM * 64];
    __shared__ float we[32 * 64];
    int t = threadIdx.x;
    for (int i = t; i < KDIM * 64; i += 256) wq[i] = Wq[i];
    for (int i = t; i < 32 * 64; i += 256) we[i] = We[i];
    __syncthreads();
    for (int idx = t; idx < KDIM * 64; idx += 256) {
        int K = idx >> 6, col = idx & 63;
        float s = 0.f;
        if (H == 2) {
            int h = col >> 5, j = col & 31;
            #pragma unroll 8
            for (int c = 0; c < 32; ++c)
                s = fmaf(wq[K * 64 + h * 32 + c], we[j * 64 + h * 32 + c], s);
        } else {
            int j = col;
            if (j < 32) {
                #pragma unroll 8
                for (int c = 0; c < 64; ++c)
                    s = fmaf(wq[K * 64 + c], we[j * 64 + c], s);
            }
        }
        Wg[idx] = s;
    }
    if (t < 64) {
        float s = 0.f;
        if (H == 2) {
            int h = t >> 5, j = t & 31;
            for (int c = 0; c < 32; ++c)
                s = fmaf(bq[h * 32 + c], we[j * 64 + h * 32 + c], s);
        } else {
            if (t < 32)
                for (int c = 0; c < 64; ++c)
                    s = fmaf(bq[c], we[t * 64 + c], s);
        }
        bg[t] = s;
    }
}

__global__ __launch_bounds__(256) void wg_build_both(
    const float* __restrict__ Wq1, const float* __restrict__ bq1,
    const float* __restrict__ We1, float* __restrict__ Wg1, float* __restrict__ bg1,
    const float* __restrict__ Wq2, const float* __restrict__ bq2,
    const float* __restrict__ We2, float* __restrict__ Wg2, float* __restrict__ bg2)
{
    if (blockIdx.x == 0) wg_dev<128, 2>(Wq1, bq1, We1, Wg1, bg1);
    else                 wg_dev<64, 1>(Wq2, bq2, We2, Wg2, bg2);
}

// ============================ weight transpose+bf16 prep ============================
__device__ __forceinline__ const float* sel5(int m, const float* a, const float* b,
    const float* c, const float* d, const float* e) {
    switch (m) { case 0: return a; case 1: return b; case 2: return c;
                 case 3: return d; default: return e; }
}

__global__ __launch_bounds__(256) void prep_weights(
    const float* Wq1, const float* Wg1, const float* Wk1, const float* Wv1, const float* Ws1,
    const float* bq1, const float* bg1, const float* bk1, const float* bv1, const float* bs1,
    const float* Wq2, const float* Wg2, const float* Wk2, const float* Wv2, const float* Ws2,
    const float* bq2, const float* bg2, const float* bk2, const float* bv2, const float* bs2,
    ushort_t* Wtb1, float* bcat1, ushort_t* Wtb2, float* bcat2)
{
    const int T1 = 320 * 128, T2 = 320 * 64;
    int stride = gridDim.x * blockDim.x;
    for (int i = blockIdx.x * blockDim.x + threadIdx.x; i < T1 + T2 + 640; i += stride) {
        if (i < T1) {
            int col = i / 128, kk = i % 128;
            int m = col >> 6, c = col & 63;
            const float* W = sel5(m, Wq1, Wg1, Wk1, Wv1, Ws1);
            Wtb1[i] = (ushort_t)bf16rne(W[kk * 64 + c]);
        } else if (i < T1 + T2) {
            int j = i - T1;
            int col = j / 64, kk = j % 64;
            int m = col >> 6, c = col & 63;
            const float* W = sel5(m, Wq2, Wg2, Wk2, Wv2, Ws2);
            Wtb2[j] = (ushort_t)bf16rne(W[kk * 64 + c]);
        } else {
            int j = i - T1 - T2;
            if (j < 320) {
                const float* b = sel5(j >> 6, bq1, bg1, bk1, bv1, bs1);
                bcat1[j] = b[j & 63];
            } else {
                j -= 320;
                const float* b = sel5(j >> 6, bq2, bg2, bk2, bv2, bs2);
                bcat2[j] = b[j & 63];
            }
        }
    }
}

// ============================ MFMA node GEMM (round-11 proven) ============================
template<int K, typename TIN>
__global__ __launch_bounds__(256) void gemm_mfma(
    const TIN* __restrict__ xin,          // [N][K]
    const ushort_t* __restrict__ Wtb,     // [320][K] bf16
    const float* __restrict__ bcat,       // [320]
    unsigned* __restrict__ qgp,           // [N][64] pack(q,g)
    unsigned* __restrict__ kvp,           // [N][64] pack(k,v)
    float* __restrict__ sk)               // [N][64]
{
    constexpr int KP = K + 8;
    __shared__ ushort_t As[32][KP];

    int t = threadIdx.x;
    int lane = t & 63, w = t >> 6;
    int m0 = blockIdx.x * 32;
    int cl = lane & 15;
    int q4 = lane >> 4;
    int col = w * 16 + cl;

    short8 bfrag[5][K / 32];
    #pragma unroll
    for (int m = 0; m < 5; ++m)
        #pragma unroll
        for (int ks = 0; ks < K / 32; ++ks)
            bfrag[m][ks] = *(const short8*)&Wtb[(size_t)(m * 64 + col) * K + ks * 32 + q4 * 8];
    float bias[5];
    #pragma unroll
    for (int m = 0; m < 5; ++m) bias[m] = bcat[m * 64 + col];

    if constexpr (sizeof(TIN) == 4) {
        constexpr int C4 = K / 4;
        #pragma unroll
        for (int it = 0; it < 32 * C4 / 256; ++it) {
            int idx = it * 256 + t;
            int row = idx / C4, c4 = idx % C4;
            float4 xv = *(const float4*)&((const float*)xin)[(size_t)(m0 + row) * K + c4 * 4];
            *(uint2*)&As[row][c4 * 4] = make_uint2(pack2(xv.x, xv.y), pack2(xv.z, xv.w));
        }
    } else {
        constexpr int C4 = K / 4;
        #pragma unroll
        for (int it = 0; it < 32 * C4 / 256; ++it) {
            int idx = it * 256 + t;
            int row = idx / C4, c4 = idx % C4;
            uint2 u = *(const uint2*)&((const ushort_t*)xin)[(size_t)(m0 + row) * K + c4 * 4];
            *(uint2*)&As[row][c4 * 4] = u;
        }
    }
    __syncthreads();

    f32x4 acc[5][2];
    f32x4 zero = {0.f, 0.f, 0.f, 0.f};
    #pragma unroll
    for (int m = 0; m < 5; ++m) { acc[m][0] = zero; acc[m][1] = zero; }

    #pragma unroll
    for (int ks = 0; ks < K / 32; ++ks) {
        short8 a0 = *(const short8*)&As[cl][ks * 32 + q4 * 8];
        short8 a1 = *(const short8*)&As[16 + cl][ks * 32 + q4 * 8];
        #pragma unroll
        for (int m = 0; m < 5; ++m) {
            acc[m][0] = __builtin_amdgcn_mfma_f32_16x16x32_bf16(a0, bfrag[m][ks], acc[m][0], 0, 0, 0);
            acc[m][1] = __builtin_amdgcn_mfma_f32_16x16x32_bf16(a1, bfrag[m][ks], acc[m][1], 0, 0, 0);
        }
    }

    #pragma unroll
    for (int rt = 0; rt < 2; ++rt) {
        #pragma unroll
        for (int r = 0; r < 4; ++r) {
            int row = m0 + rt * 16 + q4 * 4 + r;
            float qv = acc[0][rt][r] + bias[0];
            float gv = acc[1][rt][r] + bias[1];
            float kk = acc[2][rt][r] + bias[2];
            float vv = acc[3][rt][r] + bias[3];
            float sv = acc[4][rt][r] + bias[4];
            qgp[(size_t)row * 64 + col] = pack2(qv, gv);
            kvp[(size_t)row * 64 + col] = pack2(kk, vv);
            sk [(size_t)row * 64 + col] = sv;
        }
    }
}

// ============================ CSR edge pass v8: channel-folded ============================
// Lane l: half h=l>>5 (edge of the pair), channel-pair j=l&31 -> channels j, j+32.
// Per iteration a wave processes TWO edges: one ef load inst, 2 kvp dword loads,
// ONE reduce chain (H=1) / two 32-lane partial reduces (H=2).
// alpha = scale*(q.k[s] + ef.g[d]);  out_pre = (Σ ex*v[s] + (Σ ex*ef)@We)/Σ ex
template<int H, int CHUNK, typename OT>
__global__ __launch_bounds__(256) void edge_csr(
    const int* __restrict__ rowptr, const int2* __restrict__ es,
    const float* __restrict__ ef, const float* __restrict__ We,
    const unsigned* __restrict__ qgp, const unsigned* __restrict__ kvp,
    const float* __restrict__ sk, OT* __restrict__ out,
    float scale, int do_relu)
{
    __shared__ float Wel[32 * 64];
    __shared__ float ex_l[4][64];
    __shared__ float racc_l[4][64];
    int t = threadIdx.x;
    for (int i = t; i < 32 * 64; i += 256) Wel[i] = We[i];
    __syncthreads();

    int lane  = t & 63;
    int wslot = t >> 6;
    int h     = lane >> 5;          // which edge of the pair
    int j     = lane & 31;          // channel-pair id (channels j, j+32)

    int wid = blockIdx.x * 4 + wslot;
    int nw  = gridDim.x * 4;

    for (int d0 = wid; d0 < N_NODES; d0 += nw) {
        int d = __builtin_amdgcn_readfirstlane(d0);
        int r0 = rowptr[d], r1 = rowptr[d + 1];
        unsigned uqg0 = __builtin_nontemporal_load(&qgp[(size_t)d * 64 + j]);
        unsigned uqg1 = __builtin_nontemporal_load(&qgp[(size_t)d * 64 + j + 32]);
        float qv0 = unpack_lo(uqg0), gv0 = unpack_hi(uqg0);
        float qv1 = unpack_lo(uqg1), gv1 = unpack_hi(uqg1);

        float racc0 = 0.f, racc1 = 0.f;
        float efacc0 = 0.f, efacc1 = 0.f;
        float rden0 = 0.f, rden1 = 0.f;

        for (int c0 = r0; c0 < r1; c0 += CHUNK) {
            int rem = min(CHUNK, r1 - c0);
            long long ll = (lane < rem)
                ? __builtin_nontemporal_load((const long long*)&es[c0 + lane]) : 0LL;
            int e_l = (int)ll;
            int s_l = (int)(ll >> 32);

            // slot loads: slot covers edges (base, base+1); half h takes base+h
            float efA, efB; unsigned u0A, u1A, u0B, u1B;
            {
                int idxc = min(0 + h, rem - 1);
                int e_v = __shfl(e_l, idxc, 64);
                int s_v = __shfl(s_l, idxc, 64);
                efA = __builtin_nontemporal_load(&ef[(size_t)e_v * 32 + j]);
                const unsigned* kp = &kvp[(size_t)s_v * 64 + j];
                u0A = kp[0]; u1A = kp[32];
            }
            {
                int idxc = min(2 + h, rem - 1);
                int e_v = __shfl(e_l, idxc, 64);
                int s_v = __shfl(s_l, idxc, 64);
                efB = __builtin_nontemporal_load(&ef[(size_t)e_v * 32 + j]);
                const unsigned* kp = &kvp[(size_t)s_v * 64 + j];
                u0B = kp[0]; u1B = kp[32];
            }

            for (int i = 0; i < rem; i += 4) {
                // ---- consume slot A (edges i, i+1) ----
                {
                    bool valid = (i + h) < rem;
                    float kk0 = unpack_lo(u0A), vv0 = unpack_hi(u0A);
                    float kk1 = unpack_lo(u1A), vv1 = unpack_hi(u1A);
                    if (H == 1) {
                        float p = fmaf(qv0, kk0, fmaf(qv1, kk1, efA * gv0));
                        #pragma unroll
                        for (int off = 1; off < 32; off <<= 1) p += __shfl_xor(p, off, 64);
                        float ex = __expf(p * scale);
                        ex = valid ? ex : 0.f;
                        racc0 = fmaf(vv0, ex, racc0);
                        racc1 = fmaf(vv1, ex, racc1);
                        efacc0 = fmaf(efA, ex, efacc0);
                        rden0 += ex;
                    } else {
                        float p0 = fmaf(qv0, kk0, efA * gv0);
                        float p1 = fmaf(qv1, kk1, efA * gv1);
                        #pragma unroll
                        for (int off = 1; off < 32; off <<= 1) {
                            p0 += __shfl_xor(p0, off, 64);
                            p1 += __shfl_xor(p1, off, 64);
                        }
                        float ex0 = __expf(p0 * scale);
                        float ex1 = __expf(p1 * scale);
                        ex0 = valid ? ex0 : 0.f;
                        ex1 = valid ? ex1 : 0.f;
                        racc0 = fmaf(vv0, ex0, racc0);
                        racc1 = fmaf(vv1, ex1, racc1);
                        efacc0 = fmaf(efA, ex0, efacc0);
                        efacc1 = fmaf(efA, ex1, efacc1);
                        rden0 += ex0; rden1 += ex1;
                    }
                }
                // ---- refill slot A (edges i+4, i+5) ----
                {
                    int idxc = min(i + 4 + h, rem - 1);
                    int e_v = __shfl(e_l, idxc, 64);
                    int s_v = __shfl(s_l, idxc, 64);
                    efA = __builtin_nontemporal_load(&ef[(size_t)e_v * 32 + j]);
                    const unsigned* kp = &kvp[(size_t)s_v * 64 + j];
                    u0A = kp[0]; u1A = kp[32];
                }
                // ---- consume slot B (edges i+2, i+3) ----
                if (i + 2 < rem) {
                    bool valid = (i + 2 + h) < rem;
                    float kk0 = unpack_lo(u0B), vv0 = unpack_hi(u0B);
                    float kk1 = unpack_lo(u1B), vv1 = unpack_hi(u1B);
                    if (H == 1) {
                        float p = fmaf(qv0, kk0, fmaf(qv1, kk1, efB * gv0));
                        #pragma unroll
                        for (int off = 1; off < 32; off <<= 1) p += __shfl_xor(p, off, 64);
                        float ex = __expf(p * scale);
                        ex = valid ? ex : 0.f;
                        racc0 = fmaf(vv0, ex, racc0);
                        racc1 = fmaf(vv1, ex, racc1);
                        efacc0 = fmaf(efB, ex, efacc0);
                        rden0 += ex;
                    } else {
                        float p0 = fmaf(qv0, kk0, efB * gv0);
                        float p1 = fmaf(qv1, kk1, efB * gv1);
                        #pragma unroll
                        for (int off = 1; off < 32; off <<= 1) {
                            p0 += __shfl_xor(p0, off, 64);
                            p1 += __shfl_xor(p1, off, 64);
                        }
                        float ex0 = __expf(p0 * scale);
                        float ex1 = __expf(p1 * scale);
                        ex0 = valid ? ex0 : 0.f;
                        ex1 = valid ? ex1 : 0.f;
                        racc0 = fmaf(vv0, ex0, racc0);
                        racc1 = fmaf(vv1, ex1, racc1);
                        efacc0 = fmaf(efB, ex0, efacc0);
                        efacc1 = fmaf(efB, ex1, efacc1);
                        rden0 += ex0; rden1 += ex1;
                    }
                    // ---- refill slot B (edges i+6, i+7) ----
                    int idxc = min(i + 6 + h, rem - 1);
                    int e_v = __shfl(e_l, idxc, 64);
                    int s_v = __shfl(s_l, idxc, 64);
                    efB = __builtin_nontemporal_load(&ef[(size_t)e_v * 32 + j]);
                    const unsigned* kp = &kvp[(size_t)s_v * 64 + j];
                    u0B = kp[0]; u1B = kp[32];
                }
            }
        }

        // ---- combine halves ----
        racc0  += __shfl_xor(racc0, 32, 64);
        racc1  += __shfl_xor(racc1, 32, 64);
        efacc0 += __shfl_xor(efacc0, 32, 64);
        rden0  += __shfl_xor(rden0, 32, 64);
        if (H == 2) {
            efacc1 += __shfl_xor(efacc1, 32, 64);
            rden1  += __shfl_xor(rden1, 32, 64);
        }

        // ---- stage per-channel values to LDS (same-wave handoff) ----
        if (lane < 32) {
            racc_l[wslot][j]      = racc0;
            racc_l[wslot][j + 32] = racc1;
            ex_l[wslot][j] = efacc0;
            if (H == 2) ex_l[wslot][j + 32] = efacc1;
        }

        float mv = 0.f;
        int hoff = (H == 2) ? (h * 32) : 0;
        #pragma unroll 8
        for (int jj = 0; jj < 32; ++jj)
            mv = fmaf(ex_l[wslot][hoff + jj], Wel[jj * 64 + lane], mv);

        float rd = (H == 2) ? ((lane < 32) ? rden0 : rden1) : rden0;
        float val = (racc_l[wslot][lane] + mv) / (rd + 1e-16f)
                  + __builtin_nontemporal_load(&sk[(size_t)d * 64 + lane]);
        if (do_relu) val = fmaxf(val, 0.f);
        if constexpr (sizeof(OT) == 4)
            __builtin_nontemporal_store(val, &out[(size_t)d * 64 + lane]);
        else
            out[(size_t)d * 64 + lane] = (OT)bf16rne(val);
    }
}

extern "C" void kernel_launch(void* const* d_in, const int* in_sizes, int n_in,
                              void* d_out, int out_size, void* d_ws, size_t ws_size,
                              hipStream_t stream) {
    const float* x   = (const float*)d_in[0];
    const int*   ei  = (const int*)d_in[1];
    const float* ef  = (const float*)d_in[2];
    const float* Wq1 = (const float*)d_in[3];  const float* bq1 = (const float*)d_in[4];
    const float* Wk1 = (const float*)d_in[5];  const float* bk1 = (const float*)d_in[6];
    const float* Wv1 = (const float*)d_in[7];  const float* bv1 = (const float*)d_in[8];
    const float* We1 = (const float*)d_in[9];
    const float* Ws1 = (const float*)d_in[10]; const float* bs1 = (const float*)d_in[11];
    const float* Wq2 = (const float*)d_in[12]; const float* bq2 = (const float*)d_in[13];
    const float* Wk2 = (const float*)d_in[14]; const float* bk2 = (const float*)d_in[15];
    const float* Wv2 = (const float*)d_in[16]; const float* bv2 = (const float*)d_in[17];
    const float* We2 = (const float*)d_in[18];
    const float* Ws2 = (const float*)d_in[19]; const float* bs2 = (const float*)d_in[20];
    float* out = (float*)d_out;

    const int N = N_NODES, E = N_EDGES;
    size_t NF = (size_t)N * 64;
    unsigned* qgp  = (unsigned*)d_ws;           // N*64 u32 (bf16 q|g)
    unsigned* kvp  = qgp + NF;                  // N*64 u32 (bf16 k|v)
    float*    sk   = (float*)(kvp + NF);        // N*64 f32
    ushort_t* h1b  = (ushort_t*)(sk + NF);      // N*64 bf16 (layer-1 output)
    float*    Wg1  = (float*)(h1b + NF);        // 128*64
    float*    bg1  = Wg1 + 128 * 64;            // 64
    float*    Wg2  = bg1 + 64;                  // 64*64
    float*    bg2  = Wg2 + 64 * 64;             // 64
    ushort_t* Wtb1 = (ushort_t*)(bg2 + 64);     // 320*128 bf16
    float*    bcat1= (float*)(Wtb1 + 320 * 128);// 320
    ushort_t* Wtb2 = (ushort_t*)(bcat1 + 320);  // 320*64 bf16
    float*    bcat2= (float*)(Wtb2 + 320 * 64); // 320
    int* cnt    = (int*)(bcat2 + 320);          // N
    int* excl   = cnt + N;                      // N
    int* bsum   = excl + N;                     // 128
    int* cursor = bsum + 128;                   // N
    int* rowptr = cursor + N;                   // N+1 (+1 pad)
    int2* es    = (int2*)(rowptr + N + 2);      // E (8B-aligned)

    const int* src = ei;
    const int* dst = ei + E;

    dim3 b256(256);
    int gN    = (N + 255) / 256;
    int gN1   = (N + 1 + 255) / 256;
    int gE    = (E + 255) / 256;
    int gGemm = N / 32;                         // 3125 exactly
    int gEdge = 2048;
    int nScanB = (N + 1023) / 1024;

    // ---------------- CSR build (shared by both layers) ----------------
    hipLaunchKernelGGL(zero_int, dim3(gN), b256, 0, stream, cnt, N);
    hipLaunchKernelGGL(hist_kernel, dim3(gE), b256, 0, stream, dst, cnt);
    hipLaunchKernelGGL(scan1, dim3(nScanB), b256, 0, stream, cnt, excl, bsum, N);
    hipLaunchKernelGGL(scan2, dim3(1), dim3(128), 0, stream, bsum, nScanB);
    hipLaunchKernelGGL(scan3, dim3(gN1), b256, 0, stream, excl, bsum, rowptr, cursor, N);
    hipLaunchKernelGGL(scatter_kernel, dim3(gE), b256, 0, stream, dst, src, cursor, es);

    // ---------------- weight prep ----------------
    hipLaunchKernelGGL(wg_build_both, dim3(2), b256, 0, stream,
                       Wq1, bq1, We1, Wg1, bg1, Wq2, bq2, We2, Wg2, bg2);
    hipLaunchKernelGGL(prep_weights, dim3(64), b256, 0, stream,
                       Wq1, Wg1, Wk1, Wv1, Ws1, bq1, bg1, bk1, bv1, bs1,
                       Wq2, Wg2, Wk2, Wv2, Ws2, bq2, bg2, bk2, bv2, bs2,
                       Wtb1, bcat1, Wtb2, bcat2);

    // ---------------- layer 1: H=2, C=32, K=128 ----------------
    hipLaunchKernelGGL((gemm_mfma<128, float>), dim3(gGemm), b256, 0, stream,
                       x, Wtb1, bcat1, qgp, kvp, sk);
    hipLaunchKernelGGL((edge_csr<2, 16, ushort_t>), dim3(gEdge), b256, 0, stream,
                       rowptr, es, ef, We1, qgp, kvp, sk, h1b,
                       0.17677669529663687f, 1);

    // ---------------- layer 2: H=1, C=64, K=64 ----------------
    hipLaunchKernelGGL((gemm_mfma<64, ushort_t>), dim3(gGemm), b256, 0, stream,
                       h1b, Wtb2, bcat2, qgp, kvp, sk);
    hipLaunchKernelGGL((edge_csr<1, 16, float>), dim3(gEdge), b256, 0, stream,
                       rowptr, es, ef, We2, qgp, kvp, sk, out,
                       0.125f, 0);
}

// Round 13
// 413.631 us; speedup vs baseline: 1.0341x; 1.0341x over previous
//
#include <hip/hip_runtime.h>
#include <cstdint>
#include <cstddef>

typedef unsigned short ushort_t;
typedef __attribute__((ext_vector_type(8))) short short8;   // 8 bf16 (4 VGPRs)
typedef __attribute__((ext_vector_type(4))) float f32x4;    // MFMA acc

// Problem constants (from reference)
constexpr int N_NODES = 100000;
constexpr int N_EDGES = 1000000;

// ---- bf16 pack/unpack (RNE) ----
__device__ __forceinline__ unsigned bf16rne(float f) {
    unsigned u = __float_as_uint(f);
    return (u + 0x7FFFu + ((u >> 16) & 1u)) >> 16;
}
__device__ __forceinline__ unsigned pack2(float lo, float hi) {
    return bf16rne(lo) | (bf16rne(hi) << 16);
}
__device__ __forceinline__ float unpack_lo(unsigned u) { return __uint_as_float(u << 16); }
__device__ __forceinline__ float unpack_hi(unsigned u) { return __uint_as_float(u & 0xFFFF0000u); }
__device__ __forceinline__ float bf2f(ushort_t u) { return __uint_as_float(((unsigned)u) << 16); }

// ============================ CSR build ============================
__global__ void hist_kernel(const int* __restrict__ dst, int* __restrict__ cnt) {
    int i = blockIdx.x * blockDim.x + threadIdx.x;
    if (i < N_EDGES) atomicAdd(&cnt[dst[i]], 1);
}

__global__ __launch_bounds__(256) void scan1(const int* __restrict__ cnt,
    int* __restrict__ excl, int* __restrict__ bsum, int n) {
    __shared__ int sh[256];
    int b = blockIdx.x, t = threadIdx.x;
    int base = b * 1024 + t * 4;
    int v0 = (base + 0 < n) ? cnt[base + 0] : 0;
    int v1 = (base + 1 < n) ? cnt[base + 1] : 0;
    int v2 = (base + 2 < n) ? cnt[base + 2] : 0;
    int v3 = (base + 3 < n) ? cnt[base + 3] : 0;
    int s = v0 + v1 + v2 + v3;
    sh[t] = s;
    __syncthreads();
    for (int off = 1; off < 256; off <<= 1) {
        int val = (t >= off) ? sh[t - off] : 0;
        __syncthreads();
        sh[t] += val;
        __syncthreads();
    }
    int prefix = sh[t] - s;
    if (t == 255) bsum[b] = sh[255];
    if (base + 0 < n) excl[base + 0] = prefix;
    if (base + 1 < n) excl[base + 1] = prefix + v0;
    if (base + 2 < n) excl[base + 2] = prefix + v0 + v1;
    if (base + 3 < n) excl[base + 3] = prefix + v0 + v1 + v2;
}

__global__ __launch_bounds__(128) void scan2(int* __restrict__ bsum, int nb) {
    __shared__ int sh[128];
    int t = threadIdx.x;
    int v = (t < nb) ? bsum[t] : 0;
    sh[t] = v;
    __syncthreads();
    for (int off = 1; off < 128; off <<= 1) {
        int val = (t >= off) ? sh[t - off] : 0;
        __syncthreads();
        sh[t] += val;
        __syncthreads();
    }
    if (t < nb) bsum[t] = sh[t] - v;
}

__global__ void scan3(const int* __restrict__ excl, const int* __restrict__ bsum,
                      int* __restrict__ rowptr, int* __restrict__ cursor, int n) {
    int i = blockIdx.x * blockDim.x + threadIdx.x;
    if (i < n) { int r = excl[i] + bsum[i >> 10]; rowptr[i] = r; cursor[i] = r; }
    if (i == n) rowptr[n] = N_EDGES;
}

// scatter: dst-sorted src array AND dst-sorted bf16 edge-feature rows.
// efs rows become a SEQUENTIAL stream for the edge pass (uniform SGPR address).
__global__ void scatter_kernel(const int* __restrict__ dst, const int* __restrict__ src,
                               const float* __restrict__ ef, int* __restrict__ cursor,
                               int* __restrict__ srcs, ushort_t* __restrict__ efs) {
    int e = blockIdx.x * blockDim.x + threadIdx.x;
    if (e >= N_EDGES) return;
    int p = atomicAdd(&cursor[dst[e]], 1);
    srcs[p] = src[e];
    const float4* er = (const float4*)(ef + (size_t)e * 32);
    ushort_t* op = efs + (size_t)p * 32;
    #pragma unroll
    for (int qq = 0; qq < 4; ++qq) {
        float4 a = er[2 * qq], b = er[2 * qq + 1];
        uint4 u;
        u.x = pack2(a.x, a.y); u.y = pack2(a.z, a.w);
        u.z = pack2(b.x, b.y); u.w = pack2(b.z, b.w);
        *(uint4*)(op + 8 * qq) = u;
    }
}

// ============================ weight prep (Wg inline) ============================
// Wtb[l]: [320][K] bf16, per-col k-contiguous, matrices {q,g,k,v,s}; bcat fp32 [320].
// g columns computed inline: Wg[k,(h,j)] = sum_{c in head h} Wq[k,c]*We[j,c].
// Also zeroes cnt[] (grid-stride tail) -- hist runs in the NEXT launch.
__device__ __forceinline__ const float* sel4(int m, const float* q, const float* k,
                                             const float* v, const float* s) {
    switch (m) { case 0: return q; case 2: return k; case 3: return v; default: return s; }
}

__global__ __launch_bounds__(256) void prep_weights(
    const float* Wq1, const float* Wk1, const float* Wv1, const float* Ws1,
    const float* bq1, const float* bk1, const float* bv1, const float* bs1, const float* We1,
    const float* Wq2, const float* Wk2, const float* Wv2, const float* Ws2,
    const float* bq2, const float* bk2, const float* bv2, const float* bs2, const float* We2,
    ushort_t* Wtb1, float* bcat1, ushort_t* Wtb2, float* bcat2, int* cnt)
{
    const int T1 = 320 * 128, T2 = 320 * 64;
    int stride = gridDim.x * blockDim.x;
    for (int i = blockIdx.x * blockDim.x + threadIdx.x;
         i < T1 + T2 + 640 + N_NODES; i += stride) {
        if (i < T1) {
            int col = i / 128, kk = i % 128;
            int m = col >> 6, c = col & 63;
            float v;
            if (m == 1) {                    // g = Wq (.) We, per head
                int h = c >> 5, j = c & 31;
                float s = 0.f;
                #pragma unroll 8
                for (int cc = 0; cc < 32; ++cc)
                    s = fmaf(Wq1[kk * 64 + h * 32 + cc], We1[j * 64 + h * 32 + cc], s);
                v = s;
            } else {
                v = sel4(m, Wq1, Wk1, Wv1, Ws1)[kk * 64 + c];
            }
            Wtb1[i] = (ushort_t)bf16rne(v);
        } else if (i < T1 + T2) {
            int jj = i - T1;
            int col = jj / 64, kk = jj % 64;
            int m = col >> 6, c = col & 63;
            float v;
            if (m == 1) {
                if (c < 32) {
                    float s = 0.f;
                    #pragma unroll 8
                    for (int cc = 0; cc < 64; ++cc)
                        s = fmaf(Wq2[kk * 64 + cc], We2[c * 64 + cc], s);
                    v = s;
                } else v = 0.f;
            } else {
                v = sel4(m, Wq2, Wk2, Wv2, Ws2)[kk * 64 + c];
            }
            Wtb2[jj] = (ushort_t)bf16rne(v);
        } else if (i < T1 + T2 + 640) {
            int j = i - T1 - T2;
            if (j < 320) {
                int m = j >> 6, c = j & 63;
                float v;
                if (m == 1) {
                    int h = c >> 5, jjj = c & 31;
                    float s = 0.f;
                    for (int cc = 0; cc < 32; ++cc)
                        s = fmaf(bq1[h * 32 + cc], We1[jjj * 64 + h * 32 + cc], s);
                    v = s;
                } else v = sel4(m, bq1, bk1, bv1, bs1)[c];
                bcat1[j] = v;
            } else {
                int jl = j - 320;
                int m = jl >> 6, c = jl & 63;
                float v;
                if (m == 1) {
                    if (c < 32) {
                        float s = 0.f;
                        for (int cc = 0; cc < 64; ++cc)
                            s = fmaf(bq2[cc], We2[c * 64 + cc], s);
                        v = s;
                    } else v = 0.f;
                } else v = sel4(m, bq2, bk2, bv2, bs2)[c];
                bcat2[jl] = v;
            }
        } else {
            cnt[i - (T1 + T2 + 640)] = 0;
        }
    }
}

// ============================ MFMA node GEMM (round-11 proven, skp bf16) ============================
template<int K, typename TIN>
__global__ __launch_bounds__(256) void gemm_mfma(
    const TIN* __restrict__ xin,          // [N][K]
    const ushort_t* __restrict__ Wtb,     // [320][K] bf16
    const float* __restrict__ bcat,       // [320]
    unsigned* __restrict__ qgp,           // [N][64] pack(q,g)
    unsigned* __restrict__ kvp,           // [N][64] pack(k,v)
    ushort_t* __restrict__ skp)           // [N][64] bf16 skip
{
    constexpr int KP = K + 8;
    __shared__ ushort_t As[32][KP];

    int t = threadIdx.x;
    int lane = t & 63, w = t >> 6;
    int m0 = blockIdx.x * 32;
    int cl = lane & 15;
    int q4 = lane >> 4;
    int col = w * 16 + cl;

    short8 bfrag[5][K / 32];
    #pragma unroll
    for (int m = 0; m < 5; ++m)
        #pragma unroll
        for (int ks = 0; ks < K / 32; ++ks)
            bfrag[m][ks] = *(const short8*)&Wtb[(size_t)(m * 64 + col) * K + ks * 32 + q4 * 8];
    float bias[5];
    #pragma unroll
    for (int m = 0; m < 5; ++m) bias[m] = bcat[m * 64 + col];

    if constexpr (sizeof(TIN) == 4) {
        constexpr int C4 = K / 4;
        #pragma unroll
        for (int it = 0; it < 32 * C4 / 256; ++it) {
            int idx = it * 256 + t;
            int row = idx / C4, c4 = idx % C4;
            float4 xv = *(const float4*)&((const float*)xin)[(size_t)(m0 + row) * K + c4 * 4];
            *(uint2*)&As[row][c4 * 4] = make_uint2(pack2(xv.x, xv.y), pack2(xv.z, xv.w));
        }
    } else {
        constexpr int C4 = K / 4;
        #pragma unroll
        for (int it = 0; it < 32 * C4 / 256; ++it) {
            int idx = it * 256 + t;
            int row = idx / C4, c4 = idx % C4;
            uint2 u = *(const uint2*)&((const ushort_t*)xin)[(size_t)(m0 + row) * K + c4 * 4];
            *(uint2*)&As[row][c4 * 4] = u;
        }
    }
    __syncthreads();

    f32x4 acc[5][2];
    f32x4 zero = {0.f, 0.f, 0.f, 0.f};
    #pragma unroll
    for (int m = 0; m < 5; ++m) { acc[m][0] = zero; acc[m][1] = zero; }

    #pragma unroll
    for (int ks = 0; ks < K / 32; ++ks) {
        short8 a0 = *(const short8*)&As[cl][ks * 32 + q4 * 8];
        short8 a1 = *(const short8*)&As[16 + cl][ks * 32 + q4 * 8];
        #pragma unroll
        for (int m = 0; m < 5; ++m) {
            acc[m][0] = __builtin_amdgcn_mfma_f32_16x16x32_bf16(a0, bfrag[m][ks], acc[m][0], 0, 0, 0);
            acc[m][1] = __builtin_amdgcn_mfma_f32_16x16x32_bf16(a1, bfrag[m][ks], acc[m][1], 0, 0, 0);
        }
    }

    #pragma unroll
    for (int rt = 0; rt < 2; ++rt) {
        #pragma unroll
        for (int r = 0; r < 4; ++r) {
            int row = m0 + rt * 16 + q4 * 4 + r;
            float qv = acc[0][rt][r] + bias[0];
            float gv = acc[1][rt][r] + bias[1];
            float kk = acc[2][rt][r] + bias[2];
            float vv = acc[3][rt][r] + bias[3];
            float sv = acc[4][rt][r] + bias[4];
            qgp[(size_t)row * 64 + col] = pack2(qv, gv);
            kvp[(size_t)row * 64 + col] = pack2(kk, vv);
            skp[(size_t)row * 64 + col] = (ushort_t)bf16rne(sv);
        }
    }
}

// ============================ CSR edge pass v9 ============================
// Round-11 proven pipeline + dst-sorted SEQUENTIAL bf16 ef stream (uniform addr)
// and bf16 skip. alpha = scale*(q.k[s] + ef.g[d]);
// out_pre = (Σ ex*v[s] + (Σ ex*ef)@We)/Σ ex
template<int C, int CHUNK, typename OT>
__global__ __launch_bounds__(256) void edge_csr(
    const int* __restrict__ rowptr, const int* __restrict__ srcs,
    const ushort_t* __restrict__ efs, const float* __restrict__ We,
    const unsigned* __restrict__ qgp, const unsigned* __restrict__ kvp,
    const ushort_t* __restrict__ skp, OT* __restrict__ out,
    float scale, int do_relu)
{
    __shared__ float Wel[32 * 64];
    __shared__ float exl[4][64];
    int t = threadIdx.x;
    for (int i = t; i < 32 * 64; i += 256) Wel[i] = We[i];
    __syncthreads();

    int lane  = t & 63;
    int wslot = t >> 6;
    int col   = lane & 31;
    int hsel  = (C == 64) ? 0 : (lane >> 5);

    int wid = blockIdx.x * 4 + wslot;
    int nw  = gridDim.x * 4;

    for (int d0 = wid; d0 < N_NODES; d0 += nw) {
        int d = __builtin_amdgcn_readfirstlane(d0);
        int r0 = rowptr[d], r1 = rowptr[d + 1];
        unsigned uqg = __builtin_nontemporal_load(&qgp[(size_t)d * 64 + lane]);
        float qv = unpack_lo(uqg), gv = unpack_hi(uqg);
        float racc = 0.f, efacc = 0.f, rden = 0.f;

        for (int c0 = r0; c0 < r1; c0 += CHUNK) {
            int rem = min(CHUNK, r1 - c0);
            int s_l = (lane < rem) ? __builtin_nontemporal_load(&srcs[c0 + lane]) : 0;

            // prologue: edges 0 and 1 (clamped). ef rows are SEQUENTIAL.
            int i1 = min(1, rem - 1);
            int sA = __builtin_amdgcn_readlane(s_l, 0);
            int sB = __builtin_amdgcn_readlane(s_l, i1);
            float efA = bf2f(__builtin_nontemporal_load(&efs[(size_t)c0 * 32 + col]));
            float efB = bf2f(__builtin_nontemporal_load(&efs[(size_t)(c0 + i1) * 32 + col]));
            unsigned uA = kvp[(size_t)sA * 64 + lane];
            unsigned uB = kvp[(size_t)sB * 64 + lane];

            for (int i = 0; i < rem; i += 2) {
                int iN0 = min(i + 2, rem - 1);
                int iN1 = min(i + 3, rem - 1);
                int sN0 = __builtin_amdgcn_readlane(s_l, iN0);
                int sN1 = __builtin_amdgcn_readlane(s_l, iN1);
                float efN0 = bf2f(__builtin_nontemporal_load(&efs[(size_t)(c0 + iN0) * 32 + col]));
                float efN1 = bf2f(__builtin_nontemporal_load(&efs[(size_t)(c0 + iN1) * 32 + col]));
                unsigned uN0 = kvp[(size_t)sN0 * 64 + lane];
                unsigned uN1 = kvp[(size_t)sN1 * 64 + lane];

                {
                    float kk = unpack_lo(uA), vv = unpack_hi(uA);
                    float p = fmaf(qv, kk, efA * gv);
                    #pragma unroll
                    for (int off = C >> 1; off; off >>= 1) p += __shfl_xor(p, off, 64);
                    float ex = __expf(p * scale);
                    racc  = fmaf(vv,  ex, racc);
                    efacc = fmaf(efA, ex, efacc);
                    rden += ex;
                }
                if (i + 1 < rem) {
                    float kk = unpack_lo(uB), vv = unpack_hi(uB);
                    float p = fmaf(qv, kk, efB * gv);
                    #pragma unroll
                    for (int off = C >> 1; off; off >>= 1) p += __shfl_xor(p, off, 64);
                    float ex = __expf(p * scale);
                    racc  = fmaf(vv,  ex, racc);
                    efacc = fmaf(efB, ex, efacc);
                    rden += ex;
                }

                efA = efN0; uA = uN0;
                efB = efN1; uB = uN1;
            }
        }

        // finalize: (racc + efacc @ We) / rden + skip
        exl[wslot][lane] = efacc;
        float mv = 0.f;
        #pragma unroll 8
        for (int j = 0; j < 32; ++j)
            mv = fmaf(exl[wslot][hsel * 32 + j], Wel[j * 64 + lane], mv);
        float val = (racc + mv) / (rden + 1e-16f)
                  + bf2f(__builtin_nontemporal_load(&skp[(size_t)d * 64 + lane]));
        if (do_relu) val = fmaxf(val, 0.f);
        if constexpr (sizeof(OT) == 4)
            __builtin_nontemporal_store(val, &out[(size_t)d * 64 + lane]);
        else
            out[(size_t)d * 64 + lane] = (OT)bf16rne(val);
    }
}

extern "C" void kernel_launch(void* const* d_in, const int* in_sizes, int n_in,
                              void* d_out, int out_size, void* d_ws, size_t ws_size,
                              hipStream_t stream) {
    const float* x   = (const float*)d_in[0];
    const int*   ei  = (const int*)d_in[1];
    const float* ef  = (const float*)d_in[2];
    const float* Wq1 = (const float*)d_in[3];  const float* bq1 = (const float*)d_in[4];
    const float* Wk1 = (const float*)d_in[5];  const float* bk1 = (const float*)d_in[6];
    const float* Wv1 = (const float*)d_in[7];  const float* bv1 = (const float*)d_in[8];
    const float* We1 = (const float*)d_in[9];
    const float* Ws1 = (const float*)d_in[10]; const float* bs1 = (const float*)d_in[11];
    const float* Wq2 = (const float*)d_in[12]; const float* bq2 = (const float*)d_in[13];
    const float* Wk2 = (const float*)d_in[14]; const float* bk2 = (const float*)d_in[15];
    const float* Wv2 = (const float*)d_in[16]; const float* bv2 = (const float*)d_in[17];
    const float* We2 = (const float*)d_in[18];
    const float* Ws2 = (const float*)d_in[19]; const float* bs2 = (const float*)d_in[20];
    float* out = (float*)d_out;

    const int N = N_NODES, E = N_EDGES;
    size_t NF = (size_t)N * 64;
    unsigned* qgp  = (unsigned*)d_ws;              // N*64 u32 (bf16 q|g)
    unsigned* kvp  = qgp + NF;                     // N*64 u32 (bf16 k|v)
    ushort_t* efs  = (ushort_t*)(kvp + NF);        // E*32 bf16, dst-sorted (16B aligned)
    ushort_t* skp  = efs + (size_t)E * 32;         // N*64 bf16 skip
    ushort_t* h1b  = skp + NF;                     // N*64 bf16 (layer-1 output)
    ushort_t* Wtb1 = h1b + NF;                     // 320*128 bf16
    float*    bcat1= (float*)(Wtb1 + 320 * 128);   // 320
    ushort_t* Wtb2 = (ushort_t*)(bcat1 + 320);     // 320*64 bf16
    float*    bcat2= (float*)(Wtb2 + 320 * 64);    // 320
    int* cnt    = (int*)(bcat2 + 320);             // N
    int* excl   = cnt + N;                         // N
    int* bsum   = excl + N;                        // 128
    int* cursor = bsum + 128;                      // N
    int* rowptr = cursor + N;                      // N+1 (+1 pad)
    int* srcs   = rowptr + N + 2;                  // E (dst-sorted src)

    const int* src = ei;
    const int* dst = ei + E;

    dim3 b256(256);
    int gN1   = (N + 1 + 255) / 256;
    int gE    = (E + 255) / 256;
    int gGemm = N / 32;                            // 3125 exactly
    int gEdge = 2048;
    int nScanB = (N + 1023) / 1024;

    // ---------------- weight prep + cnt zeroing (one launch) ----------------
    hipLaunchKernelGGL(prep_weights, dim3(96), b256, 0, stream,
                       Wq1, Wk1, Wv1, Ws1, bq1, bk1, bv1, bs1, We1,
                       Wq2, Wk2, Wv2, Ws2, bq2, bk2, bv2, bs2, We2,
                       Wtb1, bcat1, Wtb2, bcat2, cnt);

    // ---------------- CSR build (shared by both layers) ----------------
    hipLaunchKernelGGL(hist_kernel, dim3(gE), b256, 0, stream, dst, cnt);
    hipLaunchKernelGGL(scan1, dim3(nScanB), b256, 0, stream, cnt, excl, bsum, N);
    hipLaunchKernelGGL(scan2, dim3(1), dim3(128), 0, stream, bsum, nScanB);
    hipLaunchKernelGGL(scan3, dim3(gN1), b256, 0, stream, excl, bsum, rowptr, cursor, N);
    hipLaunchKernelGGL(scatter_kernel, dim3(gE), b256, 0, stream,
                       dst, src, ef, cursor, srcs, efs);

    // ---------------- layer 1: H=2, C=32, K=128 ----------------
    hipLaunchKernelGGL((gemm_mfma<128, float>), dim3(gGemm), b256, 0, stream,
                       x, Wtb1, bcat1, qgp, kvp, skp);
    hipLaunchKernelGGL((edge_csr<32, 16, ushort_t>), dim3(gEdge), b256, 0, stream,
                       rowptr, srcs, efs, We1, qgp, kvp, skp, h1b,
                       0.17677669529663687f, 1);

    // ---------------- layer 2: H=1, C=64, K=64 ----------------
    hipLaunchKernelGGL((gemm_mfma<64, ushort_t>), dim3(gGemm), b256, 0, stream,
                       h1b, Wtb2, bcat2, qgp, kvp, skp);
    hipLaunchKernelGGL((edge_csr<64, 16, float>), dim3(gEdge), b256, 0, stream,
                       rowptr, srcs, efs, We2, qgp, kvp, skp, out,
                       0.125f, 0);
}